// Round 14
// baseline (584.209 us; speedup 1.0000x reference)
//
#include <hip/hip_runtime.h>
#include <hip/hip_bf16.h>
#include <cstdint>
#include <cstddef>

#define NROWS 32768
#define DDIM 256
#define KCODES 4096

typedef __attribute__((ext_vector_type(8))) short s16x8;
typedef __attribute__((ext_vector_type(4))) float f32x4;
typedef unsigned long long u64;
typedef unsigned int u32;

// ---------------- ws layout (float offsets), all 16B-aligned blocks ----------
#define WS_LOSS 0
#define WS_CNT 1
#define WS_EMAX 2
#define WS_DISTRUST 3
#define WS_NSC 4
#define WS_HIST 8                      // u32[4096]
#define WS_OFFS 4104                   // u32[4096]
#define WS_CURSOR 8200                 // u32[4096]
#define WS_LPART 12296                 // f32[4096]
#define WS_RLIST 16392                 // u32[32768]
#define WS_ESUM 49160                  // f32[1048576] (unused on fast path)
#define WS_XSQ 1097736                 // f32[32768]
#define WS_ESQ 1130504                 // f32[4096]
#define WS_IDX 1134600                 // i32[32768]
#define WS_KEY 1167368                 // u64[32768]
#define WS_TKEY 1232904                // u64[8*32768]
#define WS_TM2 1757192                 // f32[8*32768]
#define WS_LIST 2019336                // u32[32768]
#define WS_EH 2052104                  // ushort[1048576]
#define WS_EL 2576392                  // ushort[1048576]
#define WS_TOTAL 3055624
#define WS_ZERO_FLOATS 12296           // header + hist + offs + cursor

__device__ __forceinline__ float hsum16_np(const float a[16]) {
    float t3[8];
#pragma unroll
    for (int m = 0; m < 8; ++m) t3[m] = __fadd_rn(a[m + 8], a[m]);
    float t6[4];
#pragma unroll
    for (int m = 0; m < 4; ++m) t6[m] = __fadd_rn(t3[m + 4], t3[m]);
    return __fadd_rn(__fadd_rn(t6[0], t6[2]), __fadd_rn(t6[1], t6[3]));
}

__device__ __forceinline__ float np_sum_sq_128(const float* a) {
    float t[16];
#pragma unroll
    for (int l = 0; l < 16; ++l) {
        float m0 = __fmul_rn(a[l], a[l]);
        float m1 = __fmul_rn(a[16 + l], a[16 + l]);
        float m2 = __fmul_rn(a[32 + l], a[32 + l]);
        float m3 = __fmul_rn(a[48 + l], a[48 + l]);
        float m4 = __fmul_rn(a[64 + l], a[64 + l]);
        float m5 = __fmul_rn(a[80 + l], a[80 + l]);
        float m6 = __fmul_rn(a[96 + l], a[96 + l]);
        float m7 = __fmul_rn(a[112 + l], a[112 + l]);
        float s01 = __fadd_rn(m0, m1);
        float s23 = __fadd_rn(m2, m3);
        float s45 = __fadd_rn(m4, m5);
        float s67 = __fadd_rn(m6, m7);
        t[l] = __fadd_rn(__fadd_rn(s01, s23), __fadd_rn(s45, s67));
    }
    return hsum16_np(t);
}

__global__ void k_rownorm(const float* __restrict__ src, float* __restrict__ dst, int rows) {
    int r = blockIdx.x * blockDim.x + threadIdx.x;
    if (r < rows) {
        const float* p = src + ((size_t)r << 8);
        dst[r] = __fadd_rn(np_sum_sq_128(p), np_sum_sq_128(p + 128));
    }
}

// RNE bf16 from fp32 bits (normal values only here)
__device__ __forceinline__ ushort bf16_rn(float x) {
    u32 u = __float_as_uint(x);
    u32 r = (u + 0x7fffu + ((u >> 16) & 1u)) >> 16;
    return (ushort)r;
}
__device__ __forceinline__ float bf16_f(ushort h) { return __uint_as_float(((u32)h) << 16); }

// fused pack (hi/lo bf16 split) + numpy rownorm (+ optional emax)
__global__ void k_packnorm(const float* __restrict__ src, ushort* __restrict__ hi,
                           ushort* __restrict__ lo, float* __restrict__ dst,
                           u32* __restrict__ emax_u32) {
    __shared__ float lf[8][257];
    __shared__ float lsq[8];
    const int t = threadIdx.x;
    const int r8 = t >> 5, c8 = (t & 31) << 3;
    const size_t base = ((size_t)(blockIdx.x * 8 + r8) << 8) + c8;
    float4 v0 = *reinterpret_cast<const float4*>(src + base);
    float4 v1 = *reinterpret_cast<const float4*>(src + base + 4);
    float f[8] = {v0.x, v0.y, v0.z, v0.w, v1.x, v1.y, v1.z, v1.w};
    ushort h[8], l[8];
#pragma unroll
    for (int j = 0; j < 8; ++j) {
        h[j] = bf16_rn(f[j]);
        l[j] = bf16_rn(__fsub_rn(f[j], bf16_f(h[j])));
        lf[r8][c8 + j] = f[j];
    }
    *reinterpret_cast<s16x8*>(hi + base) = *reinterpret_cast<s16x8*>(h);
    *reinterpret_cast<s16x8*>(lo + base) = *reinterpret_cast<s16x8*>(l);
    __syncthreads();
    if (t < 8) {
        const float sq = __fadd_rn(np_sum_sq_128(&lf[t][0]), np_sum_sq_128(&lf[t][128]));
        dst[blockIdx.x * 8 + t] = sq;
        lsq[t] = sq;
    }
    if (emax_u32) {
        __syncthreads();
        if (t == 0) {
            float m = lsq[0];
#pragma unroll
            for (int i = 1; i < 8; ++i) m = fmaxf(m, lsq[i]);
            atomicMax(emax_u32, __float_as_uint(m));  // positive floats: bit-monotone
        }
    }
}

__device__ __forceinline__ float keyval_(u64 k) {
    u32 u = (u32)(k >> 32);
    u = (u & 0x80000000u) ? (u ^ 0x80000000u) : ~u;
    return __uint_as_float(u);
}
__device__ __forceinline__ u64 packkey(float d, u32 j) {
    u32 u = __float_as_uint(d);
    u ^= (u32)((int)u >> 31) | 0x80000000u;
    return ((u64)u << 32) | j;
}
#define KEY_INIT 0xFF8000007FFFFFFFull  // packkey(+INF, 0x7fffffff)

__device__ __forceinline__ void dma16(const void* g, void* l) {
    __builtin_amdgcn_global_load_lds(
        (const __attribute__((address_space(1))) void*)g,
        (__attribute__((address_space(3))) void*)l, 16, 0, 0);
}

// one js-chunk of MFMA work: 2 ks x {a-frag reads, 2 jp x (b-frag reads, 12 MFMAs)}
// Sequence per (q): ns0{hh,hl,lh}, ns1{hh,hl,lh} — identical to R9/R12.
__device__ __forceinline__ void mfma_js(const ushort* __restrict__ xh_s,
                                        const ushort* __restrict__ xl_s,
                                        const ushort* __restrict__ eh_s,
                                        const ushort* __restrict__ el_s,
                                        int w, int lr, int lg, int key, f32x4 acc[2][4]) {
#pragma unroll
    for (int ks = 0; ks < 2; ++ks) {
        const int off = (ks * 64 + lg * 16) ^ key;
        s16x8 axh[2], axl[2];
#pragma unroll
        for (int ns = 0; ns < 2; ++ns) {
            const int row = w * 32 + ns * 16 + lr;
            axh[ns] = *(const s16x8*)((const char*)(xh_s + row * 64) + off);
            axl[ns] = *(const s16x8*)((const char*)(xl_s + row * 64) + off);
        }
#pragma unroll
        for (int jp = 0; jp < 2; ++jp) {
            s16x8 beh[2], bel[2];
#pragma unroll
            for (int q = 0; q < 2; ++q) {
                const int row = (jp * 2 + q) * 16 + lr;
                beh[q] = *(const s16x8*)((const char*)(eh_s + row * 64) + off);
                bel[q] = *(const s16x8*)((const char*)(el_s + row * 64) + off);
            }
#pragma unroll
            for (int q = 0; q < 2; ++q) {
                const int jsub = jp * 2 + q;
#pragma unroll
                for (int ns = 0; ns < 2; ++ns) {
                    acc[ns][jsub] = __builtin_amdgcn_mfma_f32_16x16x32_bf16(
                        axh[ns], beh[q], acc[ns][jsub], 0, 0, 0);
                    acc[ns][jsub] = __builtin_amdgcn_mfma_f32_16x16x32_bf16(
                        axh[ns], bel[q], acc[ns][jsub], 0, 0, 0);
                    acc[ns][jsub] = __builtin_amdgcn_mfma_f32_16x16x32_bf16(
                        axl[ns], beh[q], acc[ns][jsub], 0, 0, 0);
                }
            }
        }
    }
}

// R13 k_mfma: JSP=2 — process 2 js per x-staging. x-DMA was the dominant serial
// phase term (2GB of 2.5GB total, re-staged once per js). Now per c: stage x +
// e(js0) -> compute js0 -> stage e(js1) -> compute js1. x DMA halves (2GB->1GB);
// barrier count unchanged (4/c x 4c x 4jsp = 64 = R9); LDS stays 80KB (e
// sub-staged in the single 16KB buffer) -> 2 blocks/CU. acc doubles to 64 f32
// (named acc0/acc1, static-indexed); persistent ~96 regs, inside the 128
// bucket pinned by waves_per_eu(4,4). Per-(n,j) MFMA chain + epilogue js-order
// bit-identical to R9/R12.
__global__ __attribute__((amdgpu_flat_work_group_size(512, 512), amdgpu_waves_per_eu(4, 4)))
void k_mfma(const ushort* __restrict__ xh_g, const ushort* __restrict__ xl_g,
            const ushort* __restrict__ eh_g, const ushort* __restrict__ el_g,
            const float* __restrict__ xsq, const float* __restrict__ esq,
            u64* __restrict__ tkey, float* __restrict__ tm2) {
    __shared__ __align__(16) ushort xh_s[16384];  // [256][64]
    __shared__ __align__(16) ushort xl_s[16384];
    __shared__ __align__(16) ushort eh_s[4096];   // [64][64]
    __shared__ __align__(16) ushort el_s[4096];

    const int tid = threadIdx.x;
    const int w = tid >> 6, l = tid & 63, lr = l & 15, lg = l >> 4;
    const int n0 = blockIdx.x * 256, jb = blockIdx.y, j0 = jb * 512;
    const int key = (lr & 7) << 4;

    float xq[8];
#pragma unroll
    for (int i = 0; i < 8; ++i)
        xq[i] = xsq[n0 + w * 32 + (i >> 2) * 16 + lg * 4 + (i & 3)];

    u64 K1[8];
    float M2[8];
#pragma unroll
    for (int i = 0; i < 8; ++i) { K1[i] = KEY_INIT; M2[i] = __uint_as_float(0x7F800000u); }

    for (int jsp = 0; jsp < 4; ++jsp) {
        const int jb0 = j0 + jsp * 128;  // js0 = jsp*2 starts here; js1 at +64
        f32x4 acc0[2][4], acc1[2][4];
#pragma unroll
        for (int a = 0; a < 2; ++a)
#pragma unroll
            for (int b = 0; b < 4; ++b) {
                acc0[a][b] = (f32x4){0.f, 0.f, 0.f, 0.f};
                acc1[a][b] = (f32x4){0.f, 0.f, 0.f, 0.f};
            }

        for (int c = 0; c < 4; ++c) {
            __syncthreads();  // prior phase's reads done (x buffer free)
#pragma unroll
            for (int p = 0; p < 4; ++p) {
                int m = tid + p * 512, r = m >> 3, cb = (m & 7) << 4;
                int so = (n0 + r) * 256 + c * 64 + ((cb ^ ((r & 7) << 4)) >> 1);
                dma16(xh_g + so, (char*)xh_s + m * 16);
                dma16(xl_g + so, (char*)xl_s + m * 16);
            }
            {
                int m = tid, r = m >> 3, cb = (m & 7) << 4;
                int so = (jb0 + r) * 256 + c * 64 + ((cb ^ ((r & 7) << 4)) >> 1);
                dma16(eh_g + so, (char*)eh_s + m * 16);
                dma16(el_g + so, (char*)el_s + m * 16);
            }
            __syncthreads();  // DMA drained (vmcnt0 before barrier)
            mfma_js(xh_s, xl_s, eh_s, el_s, w, lr, lg, key, acc0);
            __syncthreads();  // js0's e reads done (e buffer free)
            {
                int m = tid, r = m >> 3, cb = (m & 7) << 4;
                int so = (jb0 + 64 + r) * 256 + c * 64 + ((cb ^ ((r & 7) << 4)) >> 1);
                dma16(eh_g + so, (char*)eh_s + m * 16);
                dma16(el_g + so, (char*)el_s + m * 16);
            }
            __syncthreads();  // e(js1) drained
            mfma_js(xh_s, xl_s, eh_s, el_s, w, lr, lg, key, acc1);
        }
        // epilogue: js0 then js1 — same sequential js order as R9/R12
#pragma unroll
        for (int jsub = 0; jsub < 4; ++jsub) {
            const int j = jb0 + jsub * 16 + lr;
            const float eq = esq[j];
#pragma unroll
            for (int ns = 0; ns < 2; ++ns)
#pragma unroll
                for (int r = 0; r < 4; ++r) {
                    const float s = acc0[ns][jsub][r];
                    const float d = __fadd_rn(__fsub_rn(xq[ns * 4 + r], __fmul_rn(2.0f, s)), eq);
                    const u64 kk = packkey(d, (u32)j);
                    const int i8 = ns * 4 + r;
                    if (kk < K1[i8]) { M2[i8] = keyval_(K1[i8]); K1[i8] = kk; }
                    else if (d < M2[i8]) M2[i8] = d;
                }
        }
#pragma unroll
        for (int jsub = 0; jsub < 4; ++jsub) {
            const int j = jb0 + 64 + jsub * 16 + lr;
            const float eq = esq[j];
#pragma unroll
            for (int ns = 0; ns < 2; ++ns)
#pragma unroll
                for (int r = 0; r < 4; ++r) {
                    const float s = acc1[ns][jsub][r];
                    const float d = __fadd_rn(__fsub_rn(xq[ns * 4 + r], __fmul_rn(2.0f, s)), eq);
                    const u64 kk = packkey(d, (u32)j);
                    const int i8 = ns * 4 + r;
                    if (kk < K1[i8]) { M2[i8] = keyval_(K1[i8]); K1[i8] = kk; }
                    else if (d < M2[i8]) M2[i8] = d;
                }
        }
    }
    // cross-lane merge over the 16 j-lanes (masks stay in-group)
#pragma unroll
    for (int i8 = 0; i8 < 8; ++i8) {
        u64 k1 = K1[i8];
        float m2 = M2[i8];
#pragma unroll
        for (int mk = 1; mk < 16; mk <<= 1) {
            u32 klo = __shfl_xor((u32)k1, mk);
            u32 khi = __shfl_xor((u32)(k1 >> 32), mk);
            float om2 = __shfl_xor(m2, mk);
            u64 ok = ((u64)khi << 32) | klo;
            if (ok < k1) { m2 = fminf(om2, keyval_(k1)); k1 = ok; }
            else m2 = fminf(m2, keyval_(ok));
        }
        if (lr == 0) {
            const int n = n0 + w * 32 + (i8 >> 2) * 16 + lg * 4 + (i8 & 3);
            tkey[(size_t)jb * NROWS + n] = k1;
            tm2[(size_t)jb * NROWS + n] = m2;
        }
    }
}

__global__ void k_merge(const u64* __restrict__ tkey, const float* __restrict__ tm2,
                        const float* __restrict__ xsq, const float* __restrict__ emaxp,
                        u64* __restrict__ key64, u32* __restrict__ list, u32* __restrict__ cnt) {
    const int n = blockIdx.x * 256 + threadIdx.x;
    u64 k1 = tkey[n];
    float m2 = tm2[n];
#pragma unroll
    for (int jb = 1; jb < 8; ++jb) {
        u64 ok = tkey[(size_t)jb * NROWS + n];
        float om2 = tm2[(size_t)jb * NROWS + n];
        if (ok < k1) { m2 = fminf(om2, keyval_(k1)); k1 = ok; }
        else m2 = fminf(m2, keyval_(ok));
    }
    const float B = sqrtf(xsq[n] * emaxp[0]);
    const float Ed = 2.4e-4f * B + 1.5e-4f;
    if (m2 - keyval_(k1) <= 2.0f * Ed) {
        key64[n] = ~0ull;
        list[atomicAdd(cnt, 1u)] = (u32)n;
    } else {
        key64[n] = k1;
    }
}

// exact numpy-order dist(n, approx-winner) vs d~(winner): bound-slip / layout guard
__global__ void k_verify(const float* __restrict__ x, const float* __restrict__ e,
                         const float* __restrict__ xsq, const float* __restrict__ esq,
                         const float* __restrict__ emaxp, u64* __restrict__ key64,
                         u32* __restrict__ list, u32* __restrict__ cnt,
                         u32* __restrict__ distrust) {
    const int li = threadIdx.x & 15;
    const int n = blockIdx.x * 16 + (threadIdx.x >> 4);
    const u64 k = key64[n];
    const bool active = (k != ~0ull);
    const int idx = active ? (int)(k & 0xFFFu) : 0;
    const float* xr = x + ((size_t)n << 8);
    const float* er = e + ((size_t)idx << 8);
    float a = 0.0f;
#pragma unroll
    for (int g = 0; g < 4; ++g)
#pragma unroll
        for (int bb = 3; bb >= 0; --bb) {
            const int d = (g * 4 + bb) * 16 + li;
            a = __builtin_fmaf(xr[d], er[d], a);
        }
    const float s1 = __fadd_rn(__shfl_xor(a, 8), a);
    const float s2 = __fadd_rn(__shfl_xor(s1, 4), s1);
    const float u = __fadd_rn(s2, __shfl_xor(s2, 2));
    const float dot = __fadd_rn(u, __shfl_xor(u, 1));
    if (li == 0 && active) {
        const float d = __fadd_rn(__fsub_rn(xsq[n], __fmul_rn(2.0f, dot)), esq[idx]);
        const float dref = keyval_(k);
        const float B = sqrtf(xsq[n] * emaxp[0]);
        const float Ed = 2.4e-4f * B + 1.5e-4f;
        const float diff = fabsf(d - dref);
        if (diff > Ed) {
            key64[n] = ~0ull;
            list[atomicAdd(cnt, 1u)] = (u32)n;
            if (diff > 0.05f) atomicOr(distrust, 1u);
        }
    }
}

__global__ void k_distrust(const u32* __restrict__ distrust, u64* __restrict__ key64,
                           u32* __restrict__ list, u32* __restrict__ cnt) {
    if (*distrust == 0u) return;
    const int n = blockIdx.x * 256 + threadIdx.x;
    key64[n] = ~0ull;
    list[n] = (u32)n;
    if (n == 0) *cnt = (u32)NROWS;
}

// exact numpy-order argmin over a 512-k segment for 32 flagged rows
__global__ __attribute__((amdgpu_flat_work_group_size(512, 512), amdgpu_waves_per_eu(4)))
void k_exact(const float* __restrict__ x, const float* __restrict__ embed,
             const float* __restrict__ xsq, const float* __restrict__ esq,
             const u32* __restrict__ list, const u32* __restrict__ cntp,
             u64* __restrict__ key64) {
    const u32 cnt = *cntp;
    const int grp = blockIdx.x >> 3, seg = blockIdx.x & 7;
    const u32 base = (u32)grp * 32u;
    if (base >= cnt) return;

    __shared__ float xs[32][260];
    __shared__ float es[64][68];
    u64* red = (u64*)&es[0][0];

    const int tid = threadIdx.x;
    const int lane = tid & 63;
    const int w = tid >> 6;
    const int g = w >> 2;
    const int tc = lane & 15;
    const int tr = ((w & 3) << 2) + (lane >> 4);
    const int cbase = (g << 5) + tc;

#pragma unroll
    for (int p = 0; p < 4; ++p) {
        int v = tid + p * 512;
        int r = v >> 6;
        int c4 = (v & 63) << 2;
        u32 row = list[(base + (u32)r < cnt) ? base + r : base];
        const float4 f = *reinterpret_cast<const float4*>(x + ((size_t)row << 8) + c4);
        *reinterpret_cast<float4*>(&xs[r][c4]) = f;
    }

    const u32 row0 = list[(base + (u32)tr < cnt) ? base + tr : base];
    const u32 row1 = list[(base + (u32)tr + 16u < cnt) ? base + tr + 16 : base];
    const float xq0 = xsq[row0];
    const float xq1 = xsq[row1];

    u64 best0 = ~0ull, best1 = ~0ull;

    for (int ktl = 0; ktl < 8; ++ktl) {
        const int k0 = seg * 512 + ktl * 64;
        float acc[2][2][16];
#pragma unroll
        for (int i = 0; i < 2; ++i)
#pragma unroll
            for (int j = 0; j < 2; ++j)
#pragma unroll
                for (int q = 0; q < 16; ++q) acc[i][j][q] = 0.0f;

        for (int c = 0; c < 4; ++c) {
            __syncthreads();
#pragma unroll
            for (int p = 0; p < 2; ++p) {
                int v = tid + p * 512;
                int r = v >> 4;
                int c4 = (v & 15) << 2;
                const float4 f = *reinterpret_cast<const float4*>(
                    embed + ((size_t)(k0 + r) << 8) + (c << 6) + c4);
                *reinterpret_cast<float4*>(&es[r][c4]) = f;
            }
            __syncthreads();
#pragma unroll
            for (int jj = 3; jj >= 0; --jj) {
#pragma unroll
                for (int q = 0; q < 4; ++q) {
                    const int dl = ((c * 4 + jj) << 4) + (q << 2);
                    const int el = (jj << 4) + (q << 2);
                    const float4 a0 = *reinterpret_cast<const float4*>(&xs[tr][dl]);
                    const float4 a1 = *reinterpret_cast<const float4*>(&xs[tr + 16][dl]);
                    const int lb = q << 2;
#pragma unroll
                    for (int j2 = 0; j2 < 2; ++j2) {
                        const float4 b = *reinterpret_cast<const float4*>(&es[cbase + 16 * j2][el]);
                        acc[0][j2][lb + 0] = __builtin_fmaf(a0.x, b.x, acc[0][j2][lb + 0]);
                        acc[0][j2][lb + 1] = __builtin_fmaf(a0.y, b.y, acc[0][j2][lb + 1]);
                        acc[0][j2][lb + 2] = __builtin_fmaf(a0.z, b.z, acc[0][j2][lb + 2]);
                        acc[0][j2][lb + 3] = __builtin_fmaf(a0.w, b.w, acc[0][j2][lb + 3]);
                        acc[1][j2][lb + 0] = __builtin_fmaf(a1.x, b.x, acc[1][j2][lb + 0]);
                        acc[1][j2][lb + 1] = __builtin_fmaf(a1.y, b.y, acc[1][j2][lb + 1]);
                        acc[1][j2][lb + 2] = __builtin_fmaf(a1.z, b.z, acc[1][j2][lb + 2]);
                        acc[1][j2][lb + 3] = __builtin_fmaf(a1.w, b.w, acc[1][j2][lb + 3]);
                    }
                }
            }
        }
#pragma unroll
        for (int j2 = 0; j2 < 2; ++j2) {
            const int kk = k0 + cbase + 16 * j2;
            const float eq = esq[kk];
            {
                const float dist = __fadd_rn(__fsub_rn(xq0, __fmul_rn(2.0f, hsum16_np(acc[0][j2]))), eq);
                const u64 kkey = packkey(dist, (u32)kk);
                best0 = kkey < best0 ? kkey : best0;
            }
            {
                const float dist = __fadd_rn(__fsub_rn(xq1, __fmul_rn(2.0f, hsum16_np(acc[1][j2]))), eq);
                const u64 kkey = packkey(dist, (u32)kk);
                best1 = kkey < best1 ? kkey : best1;
            }
        }
    }

    __syncthreads();
    red[tr * 32 + (g << 4) + tc] = best0;
    red[(tr + 16) * 32 + (g << 4) + tc] = best1;
    __syncthreads();
    if (tid < 32) {
        u64 m = red[tid * 32];
#pragma unroll
        for (int t = 1; t < 32; ++t) {
            u64 v = red[tid * 32 + t];
            m = v < m ? v : m;
        }
        if (base + (u32)tid < cnt) atomicMin(&key64[list[base + tid]], m);
    }
}

// finalize idx + histogram + ind_out in one pass
__global__ void k_finhist(const u64* __restrict__ key64, int* __restrict__ idx,
                          u32* __restrict__ hist, float* __restrict__ ind_out) {
    const int n = blockIdx.x * 256 + threadIdx.x;
    const int k = (int)(key64[n] & 0xFFFull);
    idx[n] = k;
    atomicAdd(&hist[k], 1u);
    ind_out[n] = (float)k;
}

// fallback-path hist (reads idx directly)
__global__ void k_histidx(const int* __restrict__ idx, u32* __restrict__ hist,
                          float* __restrict__ ind_out) {
    const int n = blockIdx.x * 256 + threadIdx.x;
    const int k = idx[n];
    atomicAdd(&hist[k], 1u);
    ind_out[n] = (float)k;
}

// ---------- fallback full-exact argmin (R6 kernel, known-good) ----------
__global__ __attribute__((amdgpu_flat_work_group_size(512, 512), amdgpu_waves_per_eu(4)))
void k_argmin_full(const float* __restrict__ x, const float* __restrict__ embed,
                   const float* __restrict__ xsq, const float* __restrict__ esq,
                   int* __restrict__ out_idx) {
    __shared__ float xs[32][260];
    __shared__ float es[64][68];
    u64* red = (u64*)&es[0][0];
    const int tid = threadIdx.x;
    const int lane = tid & 63;
    const int w = tid >> 6;
    const int g = w >> 2;
    const int tc = lane & 15;
    const int tr = ((w & 3) << 2) + (lane >> 4);
    const int cbase = (g << 5) + tc;
    const int n0 = blockIdx.x * 32;
#pragma unroll
    for (int p = 0; p < 4; ++p) {
        int v = tid + p * 512;
        int r = v >> 6;
        int c4 = (v & 63) << 2;
        const float4 f = *reinterpret_cast<const float4*>(x + ((size_t)(n0 + r) << 8) + c4);
        *reinterpret_cast<float4*>(&xs[r][c4]) = f;
    }
    const float xq0 = xsq[n0 + tr];
    const float xq1 = xsq[n0 + tr + 16];
    u64 best0 = ~0ull, best1 = ~0ull;
    for (int kt = 0; kt < KCODES / 64; ++kt) {
        const int k0 = kt * 64;
        float acc[2][2][16];
#pragma unroll
        for (int i = 0; i < 2; ++i)
#pragma unroll
            for (int j = 0; j < 2; ++j)
#pragma unroll
                for (int q = 0; q < 16; ++q) acc[i][j][q] = 0.0f;
        for (int c = 0; c < 4; ++c) {
            __syncthreads();
#pragma unroll
            for (int p = 0; p < 2; ++p) {
                int v = tid + p * 512;
                int r = v >> 4;
                int c4 = (v & 15) << 2;
                const float4 f = *reinterpret_cast<const float4*>(
                    embed + ((size_t)(k0 + r) << 8) + (c << 6) + c4);
                *reinterpret_cast<float4*>(&es[r][c4]) = f;
            }
            __syncthreads();
#pragma unroll
            for (int jj = 3; jj >= 0; --jj) {
#pragma unroll
                for (int q = 0; q < 4; ++q) {
                    const int dl = ((c * 4 + jj) << 4) + (q << 2);
                    const int el = (jj << 4) + (q << 2);
                    const float4 a0 = *reinterpret_cast<const float4*>(&xs[tr][dl]);
                    const float4 a1 = *reinterpret_cast<const float4*>(&xs[tr + 16][dl]);
                    const int lb = q << 2;
#pragma unroll
                    for (int j2 = 0; j2 < 2; ++j2) {
                        const float4 b = *reinterpret_cast<const float4*>(&es[cbase + 16 * j2][el]);
                        acc[0][j2][lb + 0] = __builtin_fmaf(a0.x, b.x, acc[0][j2][lb + 0]);
                        acc[0][j2][lb + 1] = __builtin_fmaf(a0.y, b.y, acc[0][j2][lb + 1]);
                        acc[0][j2][lb + 2] = __builtin_fmaf(a0.z, b.z, acc[0][j2][lb + 2]);
                        acc[0][j2][lb + 3] = __builtin_fmaf(a0.w, b.w, acc[0][j2][lb + 3]);
                        acc[1][j2][lb + 0] = __builtin_fmaf(a1.x, b.x, acc[1][j2][lb + 0]);
                        acc[1][j2][lb + 1] = __builtin_fmaf(a1.y, b.y, acc[1][j2][lb + 1]);
                        acc[1][j2][lb + 2] = __builtin_fmaf(a1.z, b.z, acc[1][j2][lb + 2]);
                        acc[1][j2][lb + 3] = __builtin_fmaf(a1.w, b.w, acc[1][j2][lb + 3]);
                    }
                }
            }
        }
#pragma unroll
        for (int j2 = 0; j2 < 2; ++j2) {
            const int kk = k0 + cbase + 16 * j2;
            const float eq = esq[kk];
            {
                const float dist = __fadd_rn(__fsub_rn(xq0, __fmul_rn(2.0f, hsum16_np(acc[0][j2]))), eq);
                const u64 kkey = packkey(dist, (u32)kk);
                best0 = kkey < best0 ? kkey : best0;
            }
            {
                const float dist = __fadd_rn(__fsub_rn(xq1, __fmul_rn(2.0f, hsum16_np(acc[1][j2]))), eq);
                const u64 kkey = packkey(dist, (u32)kk);
                best1 = kkey < best1 ? kkey : best1;
            }
        }
    }
    __syncthreads();
    red[tr * 32 + (g << 4) + tc] = best0;
    red[(tr + 16) * 32 + (g << 4) + tc] = best1;
    __syncthreads();
    if (tid < 32) {
        u64 m = red[tid * 32];
#pragma unroll
        for (int t = 1; t < 32; ++t) {
            u64 v = red[tid * 32 + t];
            m = v < m ? v : m;
        }
        out_idx[n0 + tid] = (int)(m & 0xFFFFFFFFu);
    }
}

// ---------------- atomic-free scatter pipeline ----------------
// fused scan + cluster: both are single-block passes over hist[4096]
__global__ void k_scancluster(const u32* __restrict__ hist, u32* __restrict__ offs,
                              const float* __restrict__ cs, float* __restrict__ ncs_out,
                              float* __restrict__ n_out) {
    __shared__ u32 ts[1024];
    __shared__ float fs[1024];
    const int t = threadIdx.x;
    const u32 h0 = hist[t * 4], h1 = hist[t * 4 + 1], h2 = hist[t * 4 + 2], h3 = hist[t * 4 + 3];
    const u32 tot = h0 + h1 + h2 + h3;
    ts[t] = tot;
    const float n0_ = __fadd_rn(__fmul_rn(cs[t * 4 + 0], 0.1f), __fmul_rn((float)h0, 0.9f));
    const float n1_ = __fadd_rn(__fmul_rn(cs[t * 4 + 1], 0.1f), __fmul_rn((float)h1, 0.9f));
    const float n2_ = __fadd_rn(__fmul_rn(cs[t * 4 + 2], 0.1f), __fmul_rn((float)h2, 0.9f));
    const float n3_ = __fadd_rn(__fmul_rn(cs[t * 4 + 3], 0.1f), __fmul_rn((float)h3, 0.9f));
    ncs_out[t * 4 + 0] = n0_;
    ncs_out[t * 4 + 1] = n1_;
    ncs_out[t * 4 + 2] = n2_;
    ncs_out[t * 4 + 3] = n3_;
    fs[t] = ((n0_ + n1_) + n2_) + n3_;
    __syncthreads();
    for (int o = 1; o < 1024; o <<= 1) {
        const u32 add = (t >= o) ? ts[t - o] : 0u;
        __syncthreads();
        ts[t] += add;
        __syncthreads();
    }
    const u32 excl = ts[t] - tot;
    offs[t * 4] = excl;
    offs[t * 4 + 1] = excl + h0;
    offs[t * 4 + 2] = excl + h0 + h1;
    offs[t * 4 + 3] = excl + h0 + h1 + h2;
    for (int wd = 512; wd > 0; wd >>= 1) {
        if (t < wd) fs[t] += fs[t + wd];
        __syncthreads();
    }
    if (t == 0) n_out[0] = fs[0];
}

__global__ void k_place(const int* __restrict__ idx, u32* __restrict__ cursor,
                        const u32* __restrict__ offs, u32* __restrict__ rlist) {
    const int n = blockIdx.x * 256 + threadIdx.x;
    const int k = idx[n];
    const u32 p = atomicAdd(&cursor[k], 1u);
    rlist[offs[k] + p] = (u32)n;
}

// fused esum + norm
__global__ void k_esumnorm(const float* __restrict__ x, const u32* __restrict__ rlist,
                           const u32* __restrict__ offs, const u32* __restrict__ hist,
                           const float* __restrict__ ea, const float* __restrict__ ncs,
                           const float* __restrict__ nptr, float* __restrict__ en_out) {
    const int k = blockIdx.x;
    const int d = threadIdx.x;
    const u32 o = offs[k], c = hist[k];
    float s = 0.0f;
    for (u32 i = 0; i < c; ++i) s += x[((size_t)rlist[o + i] << 8) + d];
    const float n = nptr[0];
    const float ncsk = ncs[k];
    const float smoothed = (ncsk + 1e-5f) / (n + 4096.0f * 1e-5f) * n;
    const size_t ix = ((size_t)k << 8) + d;
    const float nea = __fadd_rn(__fmul_rn(ea[ix], 0.1f), __fmul_rn(s, 0.9f));
    en_out[ix] = nea / smoothed;
}

__global__ void k_outloss(const float* __restrict__ x, const float* __restrict__ e,
                          const int* __restrict__ idx, float* __restrict__ out,
                          float* __restrict__ lpart) {
    const int d = threadIdx.x;
    float ls = 0.0f;
#pragma unroll
    for (int r = 0; r < 8; ++r) {
        const int n = blockIdx.x * 8 + r;
        const int k = idx[n];
        const size_t xi = ((size_t)n << 8) + d;
        const float xv = x[xi];
        const float qv = e[((size_t)k << 8) + d];
        const float diff = __fsub_rn(qv, xv);
        out[xi] = __fadd_rn(xv, diff);
        ls = __builtin_fmaf(diff, diff, ls);
    }
    __shared__ float sred[256];
    sred[d] = ls;
    __syncthreads();
    for (int s = 128; s > 0; s >>= 1) {
        if (d < s) sred[d] += sred[d + s];
        __syncthreads();
    }
    if (d == 0) lpart[blockIdx.x] = sred[0];
}

__global__ void k_norm(const float* __restrict__ ea, const float* __restrict__ esum,
                       const float* __restrict__ ncs, const float* __restrict__ nptr,
                       float* __restrict__ en_out) {
    const int i = blockIdx.x * 256 + threadIdx.x;
    const int k = i >> 8;
    const float n = nptr[0];
    const float ncsk = ncs[k];
    const float smoothed = (ncsk + 1e-5f) / (n + 4096.0f * 1e-5f) * n;
    const float nea = __fadd_rn(__fmul_rn(ea[i], 0.1f), __fmul_rn(esum[i], 0.9f));
    en_out[i] = nea / smoothed;
}

__global__ void k_esum(const float* __restrict__ x, const u32* __restrict__ rlist,
                       const u32* __restrict__ offs, const u32* __restrict__ hist,
                       float* __restrict__ esum) {
    const int k = blockIdx.x;
    const int d = threadIdx.x;
    const u32 o = offs[k], c = hist[k];
    float s = 0.0f;
    for (u32 i = 0; i < c; ++i) s += x[((size_t)rlist[o + i] << 8) + d];
    esum[((size_t)k << 8) + d] = s;
}

__global__ void k_loss(const float* __restrict__ lpart, float* __restrict__ dst) {
    __shared__ float s[256];
    const int t = threadIdx.x;
    float a = 0.0f;
    for (int i = t; i < 4096; i += 256) a += lpart[i];
    s[t] = a;
    __syncthreads();
    for (int w = 128; w > 0; w >>= 1) {
        if (t < w) s[t] += s[t + w];
        __syncthreads();
    }
    if (t == 0) dst[0] = s[0] * (1.0f / 8388608.0f);
}

extern "C" void kernel_launch(void* const* d_in, const int* in_sizes, int n_in, void* d_out,
                              int out_size, void* d_ws, size_t ws_size, hipStream_t stream) {
    (void)in_sizes; (void)n_in; (void)out_size;
    const float* x = (const float*)d_in[0];
    const float* emb = (const float*)d_in[1];
    const float* cs = (const float*)d_in[2];
    const float* ea = (const float*)d_in[3];
    float* ws = (float*)d_ws;
    float* out = (float*)d_out;

    u32* w_cnt = (u32*)(ws + WS_CNT);
    float* w_emax = ws + WS_EMAX;
    u32* w_dis = (u32*)(ws + WS_DISTRUST);
    float* w_n = ws + WS_NSC;
    u32* w_hist = (u32*)(ws + WS_HIST);
    u32* w_offs = (u32*)(ws + WS_OFFS);
    u32* w_cursor = (u32*)(ws + WS_CURSOR);
    float* w_lpart = ws + WS_LPART;
    u32* w_rlist = (u32*)(ws + WS_RLIST);
    float* w_esum = ws + WS_ESUM;
    float* w_xsq = ws + WS_XSQ;
    float* w_esq = ws + WS_ESQ;
    int* w_idx = (int*)(ws + WS_IDX);
    u64* w_key = (u64*)(ws + WS_KEY);
    u64* w_tkey = (u64*)(ws + WS_TKEY);
    float* w_tm2 = ws + WS_TM2;
    u32* w_list = (u32*)(ws + WS_LIST);
    ushort* eh_g = (ushort*)(ws + WS_EH);
    ushort* el_g = (ushort*)(ws + WS_EL);

    float* o_out = out;              // [N*D]
    float* o_loss = out + 8388608;   // [1]
    float* o_ind = out + 8388609;    // [N]
    float* o_ncs = out + 8421377;    // [K]
    float* o_en = out + 8425473;     // [K*D]

    // x bf16-split packs live in the o_out region until k_outloss overwrites it
    ushort* xh_g = (ushort*)o_out;
    ushort* xl_g = (ushort*)o_out + 8388608;

    hipMemsetAsync(d_ws, 0, (size_t)WS_ZERO_FLOATS * sizeof(float), stream);

    if (ws_size >= (size_t)WS_TOTAL * sizeof(float)) {
        k_packnorm<<<NROWS / 8, 256, 0, stream>>>(x, xh_g, xl_g, w_xsq, nullptr);
        k_packnorm<<<KCODES / 8, 256, 0, stream>>>(emb, eh_g, el_g, w_esq, (u32*)w_emax);
        k_mfma<<<dim3(128, 8), 512, 0, stream>>>(xh_g, xl_g, eh_g, el_g, w_xsq, w_esq,
                                                 w_tkey, w_tm2);
        k_merge<<<128, 256, 0, stream>>>(w_tkey, w_tm2, w_xsq, w_emax, w_key, w_list, w_cnt);
        k_verify<<<2048, 256, 0, stream>>>(x, emb, w_xsq, w_esq, w_emax, w_key, w_list,
                                           w_cnt, w_dis);
        k_distrust<<<128, 256, 0, stream>>>(w_dis, w_key, w_list, w_cnt);
        k_exact<<<8192, 512, 0, stream>>>(x, emb, w_xsq, w_esq, w_list, w_cnt, w_key);
        k_finhist<<<128, 256, 0, stream>>>(w_key, w_idx, w_hist, o_ind);
        k_scancluster<<<1, 1024, 0, stream>>>(w_hist, w_offs, cs, o_ncs, w_n);
        k_place<<<128, 256, 0, stream>>>(w_idx, w_cursor, w_offs, w_rlist);
        k_esumnorm<<<KCODES, 256, 0, stream>>>(x, w_rlist, w_offs, w_hist, ea, o_ncs, w_n, o_en);
        k_outloss<<<NROWS / 8, 256, 0, stream>>>(x, emb, w_idx, o_out, w_lpart);
        k_loss<<<1, 256, 0, stream>>>(w_lpart, o_loss);
    } else {
        // fallback: exact fp32 path (no pack buffers available)
        k_rownorm<<<NROWS / 256, 256, 0, stream>>>(x, w_xsq, NROWS);
        k_rownorm<<<KCODES / 256, 256, 0, stream>>>(emb, w_esq, KCODES);
        k_argmin_full<<<NROWS / 32, 512, 0, stream>>>(x, emb, w_xsq, w_esq, w_idx);
        k_histidx<<<128, 256, 0, stream>>>(w_idx, w_hist, o_ind);
        k_scancluster<<<1, 1024, 0, stream>>>(w_hist, w_offs, cs, o_ncs, w_n);
        k_place<<<128, 256, 0, stream>>>(w_idx, w_cursor, w_offs, w_rlist);
        k_esum<<<KCODES, 256, 0, stream>>>(x, w_rlist, w_offs, w_hist, w_esum);
        k_outloss<<<NROWS / 8, 256, 0, stream>>>(x, emb, w_idx, o_out, w_lpart);
        k_norm<<<(KCODES * DDIM) / 256, 256, 0, stream>>>(ea, w_esum, o_ncs, w_n, o_en);
        k_loss<<<1, 256, 0, stream>>>(w_lpart, o_loss);
    }
}

// Round 15
// 406.776 us; speedup vs baseline: 1.4362x; 1.4362x over previous
//
#include <hip/hip_runtime.h>
#include <hip/hip_bf16.h>
#include <cstdint>
#include <cstddef>

#define NROWS 32768
#define DDIM 256
#define KCODES 4096

typedef __attribute__((ext_vector_type(8))) short s16x8;
typedef __attribute__((ext_vector_type(4))) float f32x4;
typedef unsigned long long u64;
typedef unsigned int u32;

// ---------------- ws layout (float offsets), all 16B-aligned blocks ----------
#define WS_LOSS 0
#define WS_CNT 1
#define WS_EMAX 2
#define WS_DISTRUST 3
#define WS_NSC 4
#define WS_HIST 8                      // u32[4096]
#define WS_OFFS 4104                   // u32[4096]
#define WS_CURSOR 8200                 // u32[4096]
#define WS_LPART 12296                 // f32[4096]
#define WS_RLIST 16392                 // u32[32768]
#define WS_ESUM 49160                  // f32[1048576] (unused on fast path)
#define WS_XSQ 1097736                 // f32[32768]
#define WS_ESQ 1130504                 // f32[4096]
#define WS_IDX 1134600                 // i32[32768]
#define WS_KEY 1167368                 // u64[32768]
#define WS_TKEY 1232904                // u64[8*32768]
#define WS_TM2 1757192                 // f32[8*32768]
#define WS_LIST 2019336                // u32[32768]
#define WS_EH 2052104                  // ushort[1048576]
#define WS_EL 2576392                  // ushort[1048576]
#define WS_TOTAL 3055624
#define WS_ZERO_FLOATS 12296           // header + hist + offs + cursor

__device__ __forceinline__ float hsum16_np(const float a[16]) {
    float t3[8];
#pragma unroll
    for (int m = 0; m < 8; ++m) t3[m] = __fadd_rn(a[m + 8], a[m]);
    float t6[4];
#pragma unroll
    for (int m = 0; m < 4; ++m) t6[m] = __fadd_rn(t3[m + 4], t3[m]);
    return __fadd_rn(__fadd_rn(t6[0], t6[2]), __fadd_rn(t6[1], t6[3]));
}

__device__ __forceinline__ float np_sum_sq_128(const float* a) {
    float t[16];
#pragma unroll
    for (int l = 0; l < 16; ++l) {
        float m0 = __fmul_rn(a[l], a[l]);
        float m1 = __fmul_rn(a[16 + l], a[16 + l]);
        float m2 = __fmul_rn(a[32 + l], a[32 + l]);
        float m3 = __fmul_rn(a[48 + l], a[48 + l]);
        float m4 = __fmul_rn(a[64 + l], a[64 + l]);
        float m5 = __fmul_rn(a[80 + l], a[80 + l]);
        float m6 = __fmul_rn(a[96 + l], a[96 + l]);
        float m7 = __fmul_rn(a[112 + l], a[112 + l]);
        float s01 = __fadd_rn(m0, m1);
        float s23 = __fadd_rn(m2, m3);
        float s45 = __fadd_rn(m4, m5);
        float s67 = __fadd_rn(m6, m7);
        t[l] = __fadd_rn(__fadd_rn(s01, s23), __fadd_rn(s45, s67));
    }
    return hsum16_np(t);
}

__global__ void k_rownorm(const float* __restrict__ src, float* __restrict__ dst, int rows) {
    int r = blockIdx.x * blockDim.x + threadIdx.x;
    if (r < rows) {
        const float* p = src + ((size_t)r << 8);
        dst[r] = __fadd_rn(np_sum_sq_128(p), np_sum_sq_128(p + 128));
    }
}

// RNE bf16 from fp32 bits (normal values only here)
__device__ __forceinline__ ushort bf16_rn(float x) {
    u32 u = __float_as_uint(x);
    u32 r = (u + 0x7fffu + ((u >> 16) & 1u)) >> 16;
    return (ushort)r;
}
__device__ __forceinline__ float bf16_f(ushort h) { return __uint_as_float(((u32)h) << 16); }

// fused pack (hi/lo bf16 split) + numpy rownorm (+ optional emax)
__global__ void k_packnorm(const float* __restrict__ src, ushort* __restrict__ hi,
                           ushort* __restrict__ lo, float* __restrict__ dst,
                           u32* __restrict__ emax_u32) {
    __shared__ float lf[8][257];
    __shared__ float lsq[8];
    const int t = threadIdx.x;
    const int r8 = t >> 5, c8 = (t & 31) << 3;
    const size_t base = ((size_t)(blockIdx.x * 8 + r8) << 8) + c8;
    float4 v0 = *reinterpret_cast<const float4*>(src + base);
    float4 v1 = *reinterpret_cast<const float4*>(src + base + 4);
    float f[8] = {v0.x, v0.y, v0.z, v0.w, v1.x, v1.y, v1.z, v1.w};
    ushort h[8], l[8];
#pragma unroll
    for (int j = 0; j < 8; ++j) {
        h[j] = bf16_rn(f[j]);
        l[j] = bf16_rn(__fsub_rn(f[j], bf16_f(h[j])));
        lf[r8][c8 + j] = f[j];
    }
    *reinterpret_cast<s16x8*>(hi + base) = *reinterpret_cast<s16x8*>(h);
    *reinterpret_cast<s16x8*>(lo + base) = *reinterpret_cast<s16x8*>(l);
    __syncthreads();
    if (t < 8) {
        const float sq = __fadd_rn(np_sum_sq_128(&lf[t][0]), np_sum_sq_128(&lf[t][128]));
        dst[blockIdx.x * 8 + t] = sq;
        lsq[t] = sq;
    }
    if (emax_u32) {
        __syncthreads();
        if (t == 0) {
            float m = lsq[0];
#pragma unroll
            for (int i = 1; i < 8; ++i) m = fmaxf(m, lsq[i]);
            atomicMax(emax_u32, __float_as_uint(m));  // positive floats: bit-monotone
        }
    }
}

__device__ __forceinline__ float keyval_(u64 k) {
    u32 u = (u32)(k >> 32);
    u = (u & 0x80000000u) ? (u ^ 0x80000000u) : ~u;
    return __uint_as_float(u);
}
__device__ __forceinline__ u64 packkey(float d, u32 j) {
    u32 u = __float_as_uint(d);
    u ^= (u32)((int)u >> 31) | 0x80000000u;
    return ((u64)u << 32) | j;
}
#define KEY_INIT 0xFF8000007FFFFFFFull  // packkey(+INF, 0x7fffffff)

__device__ __forceinline__ void dma16(const void* g, void* l) {
    __builtin_amdgcn_global_load_lds(
        (const __attribute__((address_space(1))) void*)g,
        (__attribute__((address_space(3))) void*)l, 16, 0, 0);
}

// Approx distances via bf16-split MFMA — R9 body (known-good ~234us: VGPR 64,
// 80KB LDS, 2 blocks/CU, zero bank conflicts). Structural plateau of the
// 2-barrier-per-phase schedule (MfmaUtil ~40%). All register-hungrier variants
// (reg-prefetch R3/R4, DMA-dbuf R5, frags-in-reg R10, JSP=2 R13) were spilled
// by the allocator (scratch or LDS), each costing 2-100x in memory traffic.
__global__ __attribute__((amdgpu_flat_work_group_size(512, 512), amdgpu_waves_per_eu(4, 4)))
void k_mfma(const ushort* __restrict__ xh_g, const ushort* __restrict__ xl_g,
            const ushort* __restrict__ eh_g, const ushort* __restrict__ el_g,
            const float* __restrict__ xsq, const float* __restrict__ esq,
            u64* __restrict__ tkey, float* __restrict__ tm2) {
    __shared__ __align__(16) ushort xh_s[16384];  // [256][64]
    __shared__ __align__(16) ushort xl_s[16384];
    __shared__ __align__(16) ushort eh_s[4096];   // [64][64]
    __shared__ __align__(16) ushort el_s[4096];

    const int tid = threadIdx.x;
    const int w = tid >> 6, l = tid & 63, lr = l & 15, lg = l >> 4;
    const int n0 = blockIdx.x * 256, jb = blockIdx.y, j0 = jb * 512;
    const int key = (lr & 7) << 4;

    float xq[8];
#pragma unroll
    for (int i = 0; i < 8; ++i)
        xq[i] = xsq[n0 + w * 32 + (i >> 2) * 16 + lg * 4 + (i & 3)];

    u64 K1[8];
    float M2[8];
#pragma unroll
    for (int i = 0; i < 8; ++i) { K1[i] = KEY_INIT; M2[i] = __uint_as_float(0x7F800000u); }

    for (int js = 0; js < 8; ++js) {
        const int jbase = j0 + js * 64;
        f32x4 acc[2][4];
#pragma unroll
        for (int a = 0; a < 2; ++a)
#pragma unroll
            for (int b = 0; b < 4; ++b) acc[a][b] = (f32x4){0.f, 0.f, 0.f, 0.f};

        for (int c = 0; c < 4; ++c) {
            __syncthreads();  // prior phase's reads done
#pragma unroll
            for (int p = 0; p < 4; ++p) {
                int m = tid + p * 512, r = m >> 3, cb = (m & 7) << 4;
                int so = (n0 + r) * 256 + c * 64 + ((cb ^ ((r & 7) << 4)) >> 1);
                dma16(xh_g + so, (char*)xh_s + m * 16);
                dma16(xl_g + so, (char*)xl_s + m * 16);
            }
            {
                int m = tid, r = m >> 3, cb = (m & 7) << 4;
                int so = (jbase + r) * 256 + c * 64 + ((cb ^ ((r & 7) << 4)) >> 1);
                dma16(eh_g + so, (char*)eh_s + m * 16);
                dma16(el_g + so, (char*)el_s + m * 16);
            }
            __syncthreads();  // DMA drained (vmcnt0 before barrier)
#pragma unroll
            for (int ks = 0; ks < 2; ++ks) {
                const int off = (ks * 64 + lg * 16) ^ key;
                s16x8 axh[2], axl[2];
#pragma unroll
                for (int ns = 0; ns < 2; ++ns) {
                    const int row = w * 32 + ns * 16 + lr;
                    axh[ns] = *(const s16x8*)((const char*)(xh_s + row * 64) + off);
                    axl[ns] = *(const s16x8*)((const char*)(xl_s + row * 64) + off);
                }
#pragma unroll
                for (int jp = 0; jp < 2; ++jp) {
                    s16x8 beh[2], bel[2];
#pragma unroll
                    for (int q = 0; q < 2; ++q) {
                        const int row = (jp * 2 + q) * 16 + lr;
                        beh[q] = *(const s16x8*)((const char*)(eh_s + row * 64) + off);
                        bel[q] = *(const s16x8*)((const char*)(el_s + row * 64) + off);
                    }
#pragma unroll
                    for (int q = 0; q < 2; ++q) {
                        const int jsub = jp * 2 + q;
#pragma unroll
                        for (int ns = 0; ns < 2; ++ns) {
                            acc[ns][jsub] = __builtin_amdgcn_mfma_f32_16x16x32_bf16(
                                axh[ns], beh[q], acc[ns][jsub], 0, 0, 0);
                            acc[ns][jsub] = __builtin_amdgcn_mfma_f32_16x16x32_bf16(
                                axh[ns], bel[q], acc[ns][jsub], 0, 0, 0);
                            acc[ns][jsub] = __builtin_amdgcn_mfma_f32_16x16x32_bf16(
                                axl[ns], beh[q], acc[ns][jsub], 0, 0, 0);
                        }
                    }
                }
            }
        }
        // epilogue for this Jstep: d~ with the exact final-op sequence
#pragma unroll
        for (int jsub = 0; jsub < 4; ++jsub) {
            const int j = jbase + jsub * 16 + lr;
            const float eq = esq[j];
#pragma unroll
            for (int ns = 0; ns < 2; ++ns)
#pragma unroll
                for (int r = 0; r < 4; ++r) {
                    const float s = acc[ns][jsub][r];
                    const float d = __fadd_rn(__fsub_rn(xq[ns * 4 + r], __fmul_rn(2.0f, s)), eq);
                    const u64 kk = packkey(d, (u32)j);
                    const int i8 = ns * 4 + r;
                    if (kk < K1[i8]) { M2[i8] = keyval_(K1[i8]); K1[i8] = kk; }
                    else if (d < M2[i8]) M2[i8] = d;
                }
        }
    }
    // cross-lane merge over the 16 j-lanes (masks stay in-group)
#pragma unroll
    for (int i8 = 0; i8 < 8; ++i8) {
        u64 k1 = K1[i8];
        float m2 = M2[i8];
#pragma unroll
        for (int mk = 1; mk < 16; mk <<= 1) {
            u32 klo = __shfl_xor((u32)k1, mk);
            u32 khi = __shfl_xor((u32)(k1 >> 32), mk);
            float om2 = __shfl_xor(m2, mk);
            u64 ok = ((u64)khi << 32) | klo;
            if (ok < k1) { m2 = fminf(om2, keyval_(k1)); k1 = ok; }
            else m2 = fminf(m2, keyval_(ok));
        }
        if (lr == 0) {
            const int n = n0 + w * 32 + (i8 >> 2) * 16 + lg * 4 + (i8 & 3);
            tkey[(size_t)jb * NROWS + n] = k1;
            tm2[(size_t)jb * NROWS + n] = m2;
        }
    }
}

__global__ void k_merge(const u64* __restrict__ tkey, const float* __restrict__ tm2,
                        const float* __restrict__ xsq, const float* __restrict__ emaxp,
                        u64* __restrict__ key64, u32* __restrict__ list, u32* __restrict__ cnt) {
    const int n = blockIdx.x * 256 + threadIdx.x;
    u64 k1 = tkey[n];
    float m2 = tm2[n];
#pragma unroll
    for (int jb = 1; jb < 8; ++jb) {
        u64 ok = tkey[(size_t)jb * NROWS + n];
        float om2 = tm2[(size_t)jb * NROWS + n];
        if (ok < k1) { m2 = fminf(om2, keyval_(k1)); k1 = ok; }
        else m2 = fminf(m2, keyval_(ok));
    }
    const float B = sqrtf(xsq[n] * emaxp[0]);
    const float Ed = 2.4e-4f * B + 1.5e-4f;
    if (m2 - keyval_(k1) <= 2.0f * Ed) {
        key64[n] = ~0ull;
        list[atomicAdd(cnt, 1u)] = (u32)n;
    } else {
        key64[n] = k1;
    }
}

// exact numpy-order dist(n, approx-winner) vs d~(winner): bound-slip / layout guard
__global__ void k_verify(const float* __restrict__ x, const float* __restrict__ e,
                         const float* __restrict__ xsq, const float* __restrict__ esq,
                         const float* __restrict__ emaxp, u64* __restrict__ key64,
                         u32* __restrict__ list, u32* __restrict__ cnt,
                         u32* __restrict__ distrust) {
    const int li = threadIdx.x & 15;
    const int n = blockIdx.x * 16 + (threadIdx.x >> 4);
    const u64 k = key64[n];
    const bool active = (k != ~0ull);
    const int idx = active ? (int)(k & 0xFFFu) : 0;
    const float* xr = x + ((size_t)n << 8);
    const float* er = e + ((size_t)idx << 8);
    float a = 0.0f;
#pragma unroll
    for (int g = 0; g < 4; ++g)
#pragma unroll
        for (int bb = 3; bb >= 0; --bb) {
            const int d = (g * 4 + bb) * 16 + li;
            a = __builtin_fmaf(xr[d], er[d], a);
        }
    const float s1 = __fadd_rn(__shfl_xor(a, 8), a);
    const float s2 = __fadd_rn(__shfl_xor(s1, 4), s1);
    const float u = __fadd_rn(s2, __shfl_xor(s2, 2));
    const float dot = __fadd_rn(u, __shfl_xor(u, 1));
    if (li == 0 && active) {
        const float d = __fadd_rn(__fsub_rn(xsq[n], __fmul_rn(2.0f, dot)), esq[idx]);
        const float dref = keyval_(k);
        const float B = sqrtf(xsq[n] * emaxp[0]);
        const float Ed = 2.4e-4f * B + 1.5e-4f;
        const float diff = fabsf(d - dref);
        if (diff > Ed) {
            key64[n] = ~0ull;
            list[atomicAdd(cnt, 1u)] = (u32)n;
            if (diff > 0.05f) atomicOr(distrust, 1u);
        }
    }
}

__global__ void k_distrust(const u32* __restrict__ distrust, u64* __restrict__ key64,
                           u32* __restrict__ list, u32* __restrict__ cnt) {
    if (*distrust == 0u) return;
    const int n = blockIdx.x * 256 + threadIdx.x;
    key64[n] = ~0ull;
    list[n] = (u32)n;
    if (n == 0) *cnt = (u32)NROWS;
}

// exact numpy-order argmin over a 512-k segment for 32 flagged rows
__global__ __attribute__((amdgpu_flat_work_group_size(512, 512), amdgpu_waves_per_eu(4)))
void k_exact(const float* __restrict__ x, const float* __restrict__ embed,
             const float* __restrict__ xsq, const float* __restrict__ esq,
             const u32* __restrict__ list, const u32* __restrict__ cntp,
             u64* __restrict__ key64) {
    const u32 cnt = *cntp;
    const int grp = blockIdx.x >> 3, seg = blockIdx.x & 7;
    const u32 base = (u32)grp * 32u;
    if (base >= cnt) return;

    __shared__ float xs[32][260];
    __shared__ float es[64][68];
    u64* red = (u64*)&es[0][0];

    const int tid = threadIdx.x;
    const int lane = tid & 63;
    const int w = tid >> 6;
    const int g = w >> 2;
    const int tc = lane & 15;
    const int tr = ((w & 3) << 2) + (lane >> 4);
    const int cbase = (g << 5) + tc;

#pragma unroll
    for (int p = 0; p < 4; ++p) {
        int v = tid + p * 512;
        int r = v >> 6;
        int c4 = (v & 63) << 2;
        u32 row = list[(base + (u32)r < cnt) ? base + r : base];
        const float4 f = *reinterpret_cast<const float4*>(x + ((size_t)row << 8) + c4);
        *reinterpret_cast<float4*>(&xs[r][c4]) = f;
    }

    const u32 row0 = list[(base + (u32)tr < cnt) ? base + tr : base];
    const u32 row1 = list[(base + (u32)tr + 16u < cnt) ? base + tr + 16 : base];
    const float xq0 = xsq[row0];
    const float xq1 = xsq[row1];

    u64 best0 = ~0ull, best1 = ~0ull;

    for (int ktl = 0; ktl < 8; ++ktl) {
        const int k0 = seg * 512 + ktl * 64;
        float acc[2][2][16];
#pragma unroll
        for (int i = 0; i < 2; ++i)
#pragma unroll
            for (int j = 0; j < 2; ++j)
#pragma unroll
                for (int q = 0; q < 16; ++q) acc[i][j][q] = 0.0f;

        for (int c = 0; c < 4; ++c) {
            __syncthreads();
#pragma unroll
            for (int p = 0; p < 2; ++p) {
                int v = tid + p * 512;
                int r = v >> 4;
                int c4 = (v & 15) << 2;
                const float4 f = *reinterpret_cast<const float4*>(
                    embed + ((size_t)(k0 + r) << 8) + (c << 6) + c4);
                *reinterpret_cast<float4*>(&es[r][c4]) = f;
            }
            __syncthreads();
#pragma unroll
            for (int jj = 3; jj >= 0; --jj) {
#pragma unroll
                for (int q = 0; q < 4; ++q) {
                    const int dl = ((c * 4 + jj) << 4) + (q << 2);
                    const int el = (jj << 4) + (q << 2);
                    const float4 a0 = *reinterpret_cast<const float4*>(&xs[tr][dl]);
                    const float4 a1 = *reinterpret_cast<const float4*>(&xs[tr + 16][dl]);
                    const int lb = q << 2;
#pragma unroll
                    for (int j2 = 0; j2 < 2; ++j2) {
                        const float4 b = *reinterpret_cast<const float4*>(&es[cbase + 16 * j2][el]);
                        acc[0][j2][lb + 0] = __builtin_fmaf(a0.x, b.x, acc[0][j2][lb + 0]);
                        acc[0][j2][lb + 1] = __builtin_fmaf(a0.y, b.y, acc[0][j2][lb + 1]);
                        acc[0][j2][lb + 2] = __builtin_fmaf(a0.z, b.z, acc[0][j2][lb + 2]);
                        acc[0][j2][lb + 3] = __builtin_fmaf(a0.w, b.w, acc[0][j2][lb + 3]);
                        acc[1][j2][lb + 0] = __builtin_fmaf(a1.x, b.x, acc[1][j2][lb + 0]);
                        acc[1][j2][lb + 1] = __builtin_fmaf(a1.y, b.y, acc[1][j2][lb + 1]);
                        acc[1][j2][lb + 2] = __builtin_fmaf(a1.z, b.z, acc[1][j2][lb + 2]);
                        acc[1][j2][lb + 3] = __builtin_fmaf(a1.w, b.w, acc[1][j2][lb + 3]);
                    }
                }
            }
        }
#pragma unroll
        for (int j2 = 0; j2 < 2; ++j2) {
            const int kk = k0 + cbase + 16 * j2;
            const float eq = esq[kk];
            {
                const float dist = __fadd_rn(__fsub_rn(xq0, __fmul_rn(2.0f, hsum16_np(acc[0][j2]))), eq);
                const u64 kkey = packkey(dist, (u32)kk);
                best0 = kkey < best0 ? kkey : best0;
            }
            {
                const float dist = __fadd_rn(__fsub_rn(xq1, __fmul_rn(2.0f, hsum16_np(acc[1][j2]))), eq);
                const u64 kkey = packkey(dist, (u32)kk);
                best1 = kkey < best1 ? kkey : best1;
            }
        }
    }

    __syncthreads();
    red[tr * 32 + (g << 4) + tc] = best0;
    red[(tr + 16) * 32 + (g << 4) + tc] = best1;
    __syncthreads();
    if (tid < 32) {
        u64 m = red[tid * 32];
#pragma unroll
        for (int t = 1; t < 32; ++t) {
            u64 v = red[tid * 32 + t];
            m = v < m ? v : m;
        }
        if (base + (u32)tid < cnt) atomicMin(&key64[list[base + tid]], m);
    }
}

// finalize idx + histogram + ind_out in one pass
__global__ void k_finhist(const u64* __restrict__ key64, int* __restrict__ idx,
                          u32* __restrict__ hist, float* __restrict__ ind_out) {
    const int n = blockIdx.x * 256 + threadIdx.x;
    const int k = (int)(key64[n] & 0xFFFull);
    idx[n] = k;
    atomicAdd(&hist[k], 1u);
    ind_out[n] = (float)k;
}

// fallback-path hist (reads idx directly)
__global__ void k_histidx(const int* __restrict__ idx, u32* __restrict__ hist,
                          float* __restrict__ ind_out) {
    const int n = blockIdx.x * 256 + threadIdx.x;
    const int k = idx[n];
    atomicAdd(&hist[k], 1u);
    ind_out[n] = (float)k;
}

// ---------- fallback full-exact argmin (R6 kernel, known-good) ----------
__global__ __attribute__((amdgpu_flat_work_group_size(512, 512), amdgpu_waves_per_eu(4)))
void k_argmin_full(const float* __restrict__ x, const float* __restrict__ embed,
                   const float* __restrict__ xsq, const float* __restrict__ esq,
                   int* __restrict__ out_idx) {
    __shared__ float xs[32][260];
    __shared__ float es[64][68];
    u64* red = (u64*)&es[0][0];
    const int tid = threadIdx.x;
    const int lane = tid & 63;
    const int w = tid >> 6;
    const int g = w >> 2;
    const int tc = lane & 15;
    const int tr = ((w & 3) << 2) + (lane >> 4);
    const int cbase = (g << 5) + tc;
    const int n0 = blockIdx.x * 32;
#pragma unroll
    for (int p = 0; p < 4; ++p) {
        int v = tid + p * 512;
        int r = v >> 6;
        int c4 = (v & 63) << 2;
        const float4 f = *reinterpret_cast<const float4*>(x + ((size_t)(n0 + r) << 8) + c4);
        *reinterpret_cast<float4*>(&xs[r][c4]) = f;
    }
    const float xq0 = xsq[n0 + tr];
    const float xq1 = xsq[n0 + tr + 16];
    u64 best0 = ~0ull, best1 = ~0ull;
    for (int kt = 0; kt < KCODES / 64; ++kt) {
        const int k0 = kt * 64;
        float acc[2][2][16];
#pragma unroll
        for (int i = 0; i < 2; ++i)
#pragma unroll
            for (int j = 0; j < 2; ++j)
#pragma unroll
                for (int q = 0; q < 16; ++q) acc[i][j][q] = 0.0f;
        for (int c = 0; c < 4; ++c) {
            __syncthreads();
#pragma unroll
            for (int p = 0; p < 2; ++p) {
                int v = tid + p * 512;
                int r = v >> 4;
                int c4 = (v & 15) << 2;
                const float4 f = *reinterpret_cast<const float4*>(
                    embed + ((size_t)(k0 + r) << 8) + (c << 6) + c4);
                *reinterpret_cast<float4*>(&es[r][c4]) = f;
            }
            __syncthreads();
#pragma unroll
            for (int jj = 3; jj >= 0; --jj) {
#pragma unroll
                for (int q = 0; q < 4; ++q) {
                    const int dl = ((c * 4 + jj) << 4) + (q << 2);
                    const int el = (jj << 4) + (q << 2);
                    const float4 a0 = *reinterpret_cast<const float4*>(&xs[tr][dl]);
                    const float4 a1 = *reinterpret_cast<const float4*>(&xs[tr + 16][dl]);
                    const int lb = q << 2;
#pragma unroll
                    for (int j2 = 0; j2 < 2; ++j2) {
                        const float4 b = *reinterpret_cast<const float4*>(&es[cbase + 16 * j2][el]);
                        acc[0][j2][lb + 0] = __builtin_fmaf(a0.x, b.x, acc[0][j2][lb + 0]);
                        acc[0][j2][lb + 1] = __builtin_fmaf(a0.y, b.y, acc[0][j2][lb + 1]);
                        acc[0][j2][lb + 2] = __builtin_fmaf(a0.z, b.z, acc[0][j2][lb + 2]);
                        acc[0][j2][lb + 3] = __builtin_fmaf(a0.w, b.w, acc[0][j2][lb + 3]);
                        acc[1][j2][lb + 0] = __builtin_fmaf(a1.x, b.x, acc[1][j2][lb + 0]);
                        acc[1][j2][lb + 1] = __builtin_fmaf(a1.y, b.y, acc[1][j2][lb + 1]);
                        acc[1][j2][lb + 2] = __builtin_fmaf(a1.z, b.z, acc[1][j2][lb + 2]);
                        acc[1][j2][lb + 3] = __builtin_fmaf(a1.w, b.w, acc[1][j2][lb + 3]);
                    }
                }
            }
        }
#pragma unroll
        for (int j2 = 0; j2 < 2; ++j2) {
            const int kk = k0 + cbase + 16 * j2;
            const float eq = esq[kk];
            {
                const float dist = __fadd_rn(__fsub_rn(xq0, __fmul_rn(2.0f, hsum16_np(acc[0][j2]))), eq);
                const u64 kkey = packkey(dist, (u32)kk);
                best0 = kkey < best0 ? kkey : best0;
            }
            {
                const float dist = __fadd_rn(__fsub_rn(xq1, __fmul_rn(2.0f, hsum16_np(acc[1][j2]))), eq);
                const u64 kkey = packkey(dist, (u32)kk);
                best1 = kkey < best1 ? kkey : best1;
            }
        }
    }
    __syncthreads();
    red[tr * 32 + (g << 4) + tc] = best0;
    red[(tr + 16) * 32 + (g << 4) + tc] = best1;
    __syncthreads();
    if (tid < 32) {
        u64 m = red[tid * 32];
#pragma unroll
        for (int t = 1; t < 32; ++t) {
            u64 v = red[tid * 32 + t];
            m = v < m ? v : m;
        }
        out_idx[n0 + tid] = (int)(m & 0xFFFFFFFFu);
    }
}

// ---------------- atomic-free scatter pipeline ----------------
// fused scan + cluster: both are single-block passes over hist[4096]
__global__ void k_scancluster(const u32* __restrict__ hist, u32* __restrict__ offs,
                              const float* __restrict__ cs, float* __restrict__ ncs_out,
                              float* __restrict__ n_out) {
    __shared__ u32 ts[1024];
    __shared__ float fs[1024];
    const int t = threadIdx.x;
    const u32 h0 = hist[t * 4], h1 = hist[t * 4 + 1], h2 = hist[t * 4 + 2], h3 = hist[t * 4 + 3];
    const u32 tot = h0 + h1 + h2 + h3;
    ts[t] = tot;
    const float n0_ = __fadd_rn(__fmul_rn(cs[t * 4 + 0], 0.1f), __fmul_rn((float)h0, 0.9f));
    const float n1_ = __fadd_rn(__fmul_rn(cs[t * 4 + 1], 0.1f), __fmul_rn((float)h1, 0.9f));
    const float n2_ = __fadd_rn(__fmul_rn(cs[t * 4 + 2], 0.1f), __fmul_rn((float)h2, 0.9f));
    const float n3_ = __fadd_rn(__fmul_rn(cs[t * 4 + 3], 0.1f), __fmul_rn((float)h3, 0.9f));
    ncs_out[t * 4 + 0] = n0_;
    ncs_out[t * 4 + 1] = n1_;
    ncs_out[t * 4 + 2] = n2_;
    ncs_out[t * 4 + 3] = n3_;
    fs[t] = ((n0_ + n1_) + n2_) + n3_;
    __syncthreads();
    for (int o = 1; o < 1024; o <<= 1) {
        const u32 add = (t >= o) ? ts[t - o] : 0u;
        __syncthreads();
        ts[t] += add;
        __syncthreads();
    }
    const u32 excl = ts[t] - tot;
    offs[t * 4] = excl;
    offs[t * 4 + 1] = excl + h0;
    offs[t * 4 + 2] = excl + h0 + h1;
    offs[t * 4 + 3] = excl + h0 + h1 + h2;
    for (int wd = 512; wd > 0; wd >>= 1) {
        if (t < wd) fs[t] += fs[t + wd];
        __syncthreads();
    }
    if (t == 0) n_out[0] = fs[0];
}

__global__ void k_place(const int* __restrict__ idx, u32* __restrict__ cursor,
                        const u32* __restrict__ offs, u32* __restrict__ rlist) {
    const int n = blockIdx.x * 256 + threadIdx.x;
    const int k = idx[n];
    const u32 p = atomicAdd(&cursor[k], 1u);
    rlist[offs[k] + p] = (u32)n;
}

// fused esum + norm
__global__ void k_esumnorm(const float* __restrict__ x, const u32* __restrict__ rlist,
                           const u32* __restrict__ offs, const u32* __restrict__ hist,
                           const float* __restrict__ ea, const float* __restrict__ ncs,
                           const float* __restrict__ nptr, float* __restrict__ en_out) {
    const int k = blockIdx.x;
    const int d = threadIdx.x;
    const u32 o = offs[k], c = hist[k];
    float s = 0.0f;
    for (u32 i = 0; i < c; ++i) s += x[((size_t)rlist[o + i] << 8) + d];
    const float n = nptr[0];
    const float ncsk = ncs[k];
    const float smoothed = (ncsk + 1e-5f) / (n + 4096.0f * 1e-5f) * n;
    const size_t ix = ((size_t)k << 8) + d;
    const float nea = __fadd_rn(__fmul_rn(ea[ix], 0.1f), __fmul_rn(s, 0.9f));
    en_out[ix] = nea / smoothed;
}

__global__ void k_outloss(const float* __restrict__ x, const float* __restrict__ e,
                          const int* __restrict__ idx, float* __restrict__ out,
                          float* __restrict__ lpart) {
    const int d = threadIdx.x;
    float ls = 0.0f;
#pragma unroll
    for (int r = 0; r < 8; ++r) {
        const int n = blockIdx.x * 8 + r;
        const int k = idx[n];
        const size_t xi = ((size_t)n << 8) + d;
        const float xv = x[xi];
        const float qv = e[((size_t)k << 8) + d];
        const float diff = __fsub_rn(qv, xv);
        out[xi] = __fadd_rn(xv, diff);
        ls = __builtin_fmaf(diff, diff, ls);
    }
    __shared__ float sred[256];
    sred[d] = ls;
    __syncthreads();
    for (int s = 128; s > 0; s >>= 1) {
        if (d < s) sred[d] += sred[d + s];
        __syncthreads();
    }
    if (d == 0) lpart[blockIdx.x] = sred[0];
}

__global__ void k_norm(const float* __restrict__ ea, const float* __restrict__ esum,
                       const float* __restrict__ ncs, const float* __restrict__ nptr,
                       float* __restrict__ en_out) {
    const int i = blockIdx.x * 256 + threadIdx.x;
    const int k = i >> 8;
    const float n = nptr[0];
    const float ncsk = ncs[k];
    const float smoothed = (ncsk + 1e-5f) / (n + 4096.0f * 1e-5f) * n;
    const float nea = __fadd_rn(__fmul_rn(ea[i], 0.1f), __fmul_rn(esum[i], 0.9f));
    en_out[i] = nea / smoothed;
}

__global__ void k_esum(const float* __restrict__ x, const u32* __restrict__ rlist,
                       const u32* __restrict__ offs, const u32* __restrict__ hist,
                       float* __restrict__ esum) {
    const int k = blockIdx.x;
    const int d = threadIdx.x;
    const u32 o = offs[k], c = hist[k];
    float s = 0.0f;
    for (u32 i = 0; i < c; ++i) s += x[((size_t)rlist[o + i] << 8) + d];
    esum[((size_t)k << 8) + d] = s;
}

__global__ void k_loss(const float* __restrict__ lpart, float* __restrict__ dst) {
    __shared__ float s[256];
    const int t = threadIdx.x;
    float a = 0.0f;
    for (int i = t; i < 4096; i += 256) a += lpart[i];
    s[t] = a;
    __syncthreads();
    for (int w = 128; w > 0; w >>= 1) {
        if (t < w) s[t] += s[t + w];
        __syncthreads();
    }
    if (t == 0) dst[0] = s[0] * (1.0f / 8388608.0f);
}

extern "C" void kernel_launch(void* const* d_in, const int* in_sizes, int n_in, void* d_out,
                              int out_size, void* d_ws, size_t ws_size, hipStream_t stream) {
    (void)in_sizes; (void)n_in; (void)out_size;
    const float* x = (const float*)d_in[0];
    const float* emb = (const float*)d_in[1];
    const float* cs = (const float*)d_in[2];
    const float* ea = (const float*)d_in[3];
    float* ws = (float*)d_ws;
    float* out = (float*)d_out;

    u32* w_cnt = (u32*)(ws + WS_CNT);
    float* w_emax = ws + WS_EMAX;
    u32* w_dis = (u32*)(ws + WS_DISTRUST);
    float* w_n = ws + WS_NSC;
    u32* w_hist = (u32*)(ws + WS_HIST);
    u32* w_offs = (u32*)(ws + WS_OFFS);
    u32* w_cursor = (u32*)(ws + WS_CURSOR);
    float* w_lpart = ws + WS_LPART;
    u32* w_rlist = (u32*)(ws + WS_RLIST);
    float* w_esum = ws + WS_ESUM;
    float* w_xsq = ws + WS_XSQ;
    float* w_esq = ws + WS_ESQ;
    int* w_idx = (int*)(ws + WS_IDX);
    u64* w_key = (u64*)(ws + WS_KEY);
    u64* w_tkey = (u64*)(ws + WS_TKEY);
    float* w_tm2 = ws + WS_TM2;
    u32* w_list = (u32*)(ws + WS_LIST);
    ushort* eh_g = (ushort*)(ws + WS_EH);
    ushort* el_g = (ushort*)(ws + WS_EL);

    float* o_out = out;              // [N*D]
    float* o_loss = out + 8388608;   // [1]
    float* o_ind = out + 8388609;    // [N]
    float* o_ncs = out + 8421377;    // [K]
    float* o_en = out + 8425473;     // [K*D]

    // x bf16-split packs live in the o_out region until k_outloss overwrites it
    ushort* xh_g = (ushort*)o_out;
    ushort* xl_g = (ushort*)o_out + 8388608;

    hipMemsetAsync(d_ws, 0, (size_t)WS_ZERO_FLOATS * sizeof(float), stream);

    if (ws_size >= (size_t)WS_TOTAL * sizeof(float)) {
        k_packnorm<<<NROWS / 8, 256, 0, stream>>>(x, xh_g, xl_g, w_xsq, nullptr);
        k_packnorm<<<KCODES / 8, 256, 0, stream>>>(emb, eh_g, el_g, w_esq, (u32*)w_emax);
        k_mfma<<<dim3(128, 8), 512, 0, stream>>>(xh_g, xl_g, eh_g, el_g, w_xsq, w_esq,
                                                 w_tkey, w_tm2);
        k_merge<<<128, 256, 0, stream>>>(w_tkey, w_tm2, w_xsq, w_emax, w_key, w_list, w_cnt);
        k_verify<<<2048, 256, 0, stream>>>(x, emb, w_xsq, w_esq, w_emax, w_key, w_list,
                                           w_cnt, w_dis);
        k_distrust<<<128, 256, 0, stream>>>(w_dis, w_key, w_list, w_cnt);
        k_exact<<<8192, 512, 0, stream>>>(x, emb, w_xsq, w_esq, w_list, w_cnt, w_key);
        k_finhist<<<128, 256, 0, stream>>>(w_key, w_idx, w_hist, o_ind);
        k_scancluster<<<1, 1024, 0, stream>>>(w_hist, w_offs, cs, o_ncs, w_n);
        k_place<<<128, 256, 0, stream>>>(w_idx, w_cursor, w_offs, w_rlist);
        k_esumnorm<<<KCODES, 256, 0, stream>>>(x, w_rlist, w_offs, w_hist, ea, o_ncs, w_n, o_en);
        k_outloss<<<NROWS / 8, 256, 0, stream>>>(x, emb, w_idx, o_out, w_lpart);
        k_loss<<<1, 256, 0, stream>>>(w_lpart, o_loss);
    } else {
        // fallback: exact fp32 path (no pack buffers available)
        k_rownorm<<<NROWS / 256, 256, 0, stream>>>(x, w_xsq, NROWS);
        k_rownorm<<<KCODES / 256, 256, 0, stream>>>(emb, w_esq, KCODES);
        k_argmin_full<<<NROWS / 32, 512, 0, stream>>>(x, emb, w_xsq, w_esq, w_idx);
        k_histidx<<<128, 256, 0, stream>>>(w_idx, w_hist, o_ind);
        k_scancluster<<<1, 1024, 0, stream>>>(w_hist, w_offs, cs, o_ncs, w_n);
        k_place<<<128, 256, 0, stream>>>(w_idx, w_cursor, w_offs, w_rlist);
        k_esum<<<KCODES, 256, 0, stream>>>(x, w_rlist, w_offs, w_hist, w_esum);
        k_outloss<<<NROWS / 8, 256, 0, stream>>>(x, emb, w_idx, o_out, w_lpart);
        k_norm<<<(KCODES * DDIM) / 256, 256, 0, stream>>>(ea, w_esum, o_ncs, w_n, o_en);
        k_loss<<<1, 256, 0, stream>>>(w_lpart, o_loss);
    }
}